// Round 19
// baseline (344.418 us; speedup 1.0000x reference)
//
#include <hip/hip_runtime.h>
#include <hip/hip_fp16.h>
#include <math.h>

typedef __attribute__((ext_vector_type(4))) float f32x4;
typedef __attribute__((ext_vector_type(2))) unsigned int u32x2;

#define SB() __builtin_amdgcn_sched_barrier(0)
#define WAITV(n)                                              \
  do {                                                        \
    asm volatile("s_waitcnt vmcnt(" #n ")" ::: "memory");     \
    SB();                                                     \
  } while (0)
// inline-asm loads: invisible to SIInsertWaitcnts (no compiler vmcnt(0) drains)
// offset: 13-bit signed; immediates kept in {0,544,1088,1632} and {0,16}
#define LD2(dst, ptr, OFF)                                           \
  asm volatile("global_load_dwordx2 %0, %1, off offset:" OFF         \
               : "=v"(dst) : "v"(ptr) : "memory")
#define LD4(dst, ptr, OFF)                                           \
  asm volatile("global_load_dwordx4 %0, %1, off offset:" OFF         \
               : "=v"(dst) : "v"(ptr) : "memory")

__device__ inline float wave_max64(float v) {
#pragma unroll
  for (int off = 32; off > 0; off >>= 1) v = fmaxf(v, __shfl_xor(v, off, 64));
  return v;
}
__device__ inline float wave_sum64(float v) {
#pragma unroll
  for (int off = 32; off > 0; off >>= 1) v += __shfl_xor(v, off, 64);
  return v;
}
// wave64 max via DPP, broadcast via readlane63 (verified r4-r18)
__device__ inline float wave_max_dpp(float x) {
  int xi = __float_as_int(x);
  x = fmaxf(x, __int_as_float(__builtin_amdgcn_update_dpp(xi, xi, 0x111, 0xf, 0xf, false)));
  xi = __float_as_int(x);
  x = fmaxf(x, __int_as_float(__builtin_amdgcn_update_dpp(xi, xi, 0x112, 0xf, 0xf, false)));
  xi = __float_as_int(x);
  x = fmaxf(x, __int_as_float(__builtin_amdgcn_update_dpp(xi, xi, 0x114, 0xf, 0xf, false)));
  xi = __float_as_int(x);
  x = fmaxf(x, __int_as_float(__builtin_amdgcn_update_dpp(xi, xi, 0x118, 0xf, 0xf, false)));
  xi = __float_as_int(x);
  x = fmaxf(x, __int_as_float(__builtin_amdgcn_update_dpp(xi, xi, 0x142, 0xa, 0xf, false)));
  xi = __float_as_int(x);
  x = fmaxf(x, __int_as_float(__builtin_amdgcn_update_dpp(xi, xi, 0x143, 0xc, 0xf, false)));
  return __int_as_float(__builtin_amdgcn_readlane(__float_as_int(x), 63));
}
// lane l <- x from lane l-1; lane 0 <- 0 (DPP wave_shr:1, verified r6-r18)
__device__ inline float lane_shr1(float x) {
  return __int_as_float(__builtin_amdgcn_update_dpp(
      0, __float_as_int(x), 0x138, 0xf, 0xf, true));
}

// ---------------- k1 body: log-softmax + gather -> fp16 rows + f32 blanks ---
// 512-thr blocks, wave w handles chunk-local row tq*8+w.
// Row = 256 fp16 target probs (512 B) @ stride 544 B (non-pow2).
__device__ __forceinline__ void k1_body8(
    const float* __restrict__ lp, const int* __restrict__ targets,
    char* __restrict__ gw, float* __restrict__ qw, int t0, int T, int CB,
    int QS, int S, int b, int tq, float* rowbuf) {
  const int lane = threadIdx.x & 63;
  const int w = threadIdx.x >> 6;
  const int tloc = tq * 8 + w;
  const int t = t0 + tloc;
  if (t >= T) return;
  const int4 tg4 = *(const int4*)(targets + (size_t)b * S + 4 * lane);

  const float* row = lp + ((size_t)b * T + t) * 1024;
  const float4 v0 = *(const float4*)(row + 4 * lane);
  const float4 v1 = *(const float4*)(row + 256 + 4 * lane);
  const float4 v2 = *(const float4*)(row + 512 + 4 * lane);
  const float4 v3 = *(const float4*)(row + 768 + 4 * lane);
  float mx = fmaxf(fmaxf(fmaxf(v0.x, v0.y), fmaxf(v0.z, v0.w)),
                   fmaxf(fmaxf(v1.x, v1.y), fmaxf(v1.z, v1.w)));
  mx = fmaxf(mx, fmaxf(fmaxf(fmaxf(v2.x, v2.y), fmaxf(v2.z, v2.w)),
                       fmaxf(fmaxf(v3.x, v3.y), fmaxf(v3.z, v3.w))));
  mx = wave_max64(mx);
  float sm = __expf(v0.x - mx) + __expf(v0.y - mx) + __expf(v0.z - mx) +
             __expf(v0.w - mx) + __expf(v1.x - mx) + __expf(v1.y - mx) +
             __expf(v1.z - mx) + __expf(v1.w - mx) + __expf(v2.x - mx) +
             __expf(v2.y - mx) + __expf(v2.z - mx) + __expf(v2.w - mx) +
             __expf(v3.x - mx) + __expf(v3.y - mx) + __expf(v3.z - mx) +
             __expf(v3.w - mx);
  sm = wave_sum64(sm);
  const float lse = mx + __logf(sm);
  *(float4*)(rowbuf + 4 * lane) = v0;
  *(float4*)(rowbuf + 256 + 4 * lane) = v1;
  *(float4*)(rowbuf + 512 + 4 * lane) = v2;
  *(float4*)(rowbuf + 768 + 4 * lane) = v3;
  const float e0 = __expf(rowbuf[tg4.x] - lse);
  const float e1 = __expf(rowbuf[tg4.y] - lse);
  const float e2 = __expf(rowbuf[tg4.z] - lse);
  const float e3 = __expf(rowbuf[tg4.w] - lse);
  const unsigned h0 = __half_as_ushort(__float2half(e0));
  const unsigned h1 = __half_as_ushort(__float2half(e1));
  const unsigned h2 = __half_as_ushort(__float2half(e2));
  const unsigned h3 = __half_as_ushort(__float2half(e3));
  char* gr = gw + ((size_t)b * CB + tloc) * 544;
  *(uint2*)(gr + 8 * lane) = make_uint2(h0 | (h1 << 16), h2 | (h3 << 16));
  if (lane == 0) qw[(size_t)b * QS + tloc] = __expf(rowbuf[0] - lse);
}

__global__ __launch_bounds__(512) void k1_std8(
    const float* __restrict__ lp, const int* __restrict__ targets,
    char* __restrict__ gw, float* __restrict__ qw, int t0, int T, int CB,
    int QS, int S) {
  __shared__ __align__(16) float lds[8192];
  k1_body8(lp, targets, gw, qw, t0, T, CB, QS, S, blockIdx.y, blockIdx.x,
           lds + (threadIdx.x >> 6) * 1024);
}

// ---------------- k2 body: alpha recursion, fp16 rows, 2-set asm pipe -------
#define DECL8(P)                                                     \
  u32x2 P##v0, P##v1, P##v2, P##v3, P##v4, P##v5, P##v6, P##v7;      \
  f32x4 P##qL, P##qH;

// 10 loads/group: 8x LD2 rows (two bases 4 rows = 2176 B apart) + 2x LD4 blanks
#define ISS8(P)                                                      \
  do {                                                               \
    LD2(P##v0, gpA_, "0");    LD2(P##v1, gpA_, "544");               \
    LD2(P##v2, gpA_, "1088"); LD2(P##v3, gpA_, "1632");              \
    LD2(P##v4, gpB_, "0");    LD2(P##v5, gpB_, "544");               \
    LD2(P##v6, gpB_, "1088"); LD2(P##v7, gpB_, "1632");              \
    LD4(P##qL, gq_, "0");     LD4(P##qH, gq_, "16");                 \
    gpA_ += 4352; gpB_ += 4352; gq_ += 8;                            \
  } while (0)

#define KSR(du, qv)                                                           \
  {                                                                           \
    const float px = __half2float(__ushort_as_half((unsigned short)((du).x))); \
    const float py = __half2float(__ushort_as_half((unsigned short)((du).x >> 16))); \
    const float pz = __half2float(__ushort_as_half((unsigned short)((du).y))); \
    const float pw = __half2float(__ushort_as_half((unsigned short)((du).y >> 16))); \
    const float hm1 = lane_shr1(a7);                                          \
    const float n0 = (a0 + hm1) * (qv);                                       \
    const float n1 = __fmaf_rn(sk1, hm1, a1 + a0) * px;                       \
    const float n2 = (a2 + a1) * (qv);                                        \
    const float n3 = __fmaf_rn(sk3, a1, a3 + a2) * py;                        \
    const float n4 = (a4 + a3) * (qv);                                        \
    const float n5 = __fmaf_rn(sk5, a3, a5 + a4) * pz;                        \
    const float n6 = (a6 + a5) * (qv);                                        \
    const float n7 = __fmaf_rn(sk7, a5, a7 + a6) * pw;                        \
    const float n8 = (a8 + a7) * (qv);                                        \
    a0 = n0; a1 = n1; a2 = n2; a3 = n3; a4 = n4;                              \
    a5 = n5; a6 = n6; a7 = n7; a8 = n8;                                       \
  }

#define RESC()                                                            \
  {                                                                       \
    float m_ = fmaxf(fmaxf(fmaxf(fmaxf(a0, a1), fmaxf(a2, a3)),           \
                           fmaxf(fmaxf(a4, a5), fmaxf(a6, a7))), a8);     \
    m_ = wave_max_dpp(m_);                                                \
    const int e_ =                                                        \
        (m_ > 0.f) ? (int)((__float_as_uint(m_) >> 23) & 255u) - 127 : 0; \
    a0 = ldexpf(a0, -e_); a1 = ldexpf(a1, -e_); a2 = ldexpf(a2, -e_);     \
    a3 = ldexpf(a3, -e_); a4 = ldexpf(a4, -e_); a5 = ldexpf(a5, -e_);     \
    a6 = ldexpf(a6, -e_); a7 = ldexpf(a7, -e_); a8 = ldexpf(a8, -e_);     \
    E += e_;                                                              \
  }

#define COMP8(P, rem)                                            \
  do {                                                           \
    if ((rem) >= 8) {                                            \
      KSR(P##v0, (P##qL).x) KSR(P##v1, (P##qL).y)                \
      KSR(P##v2, (P##qL).z) KSR(P##v3, (P##qL).w)                \
      KSR(P##v4, (P##qH).x) KSR(P##v5, (P##qH).y)                \
      KSR(P##v6, (P##qH).z) KSR(P##v7, (P##qH).w) RESC()         \
    } else {                                                     \
      KSR(P##v0, (P##qL).x)                                      \
      if ((rem) > 1) KSR(P##v1, (P##qL).y)                       \
      if ((rem) > 2) KSR(P##v2, (P##qL).z)                       \
      if ((rem) > 3) KSR(P##v3, (P##qL).w)                       \
      if ((rem) > 4) KSR(P##v4, (P##qH).x)                       \
      if ((rem) > 5) KSR(P##v5, (P##qH).y)                       \
      if ((rem) > 6) KSR(P##v6, (P##qH).z)                       \
      RESC()                                                     \
    }                                                            \
  } while (0)

template <int R0, int LAST>
__device__ __forceinline__ void k2_body(
    const char* __restrict__ gb, const float* __restrict__ qb,
    const int* __restrict__ targets, const int* __restrict__ in_len,
    const int* __restrict__ tgt_len, float* __restrict__ alpha_g,
    int* __restrict__ exp_g, float* __restrict__ tot, int b, int t0, int Tc,
    int S, float* fin) {
  const int lane = threadIdx.x & 63;
  const int len = in_len[b];
  const int tl = tgt_len[b];
  const int* tg = targets + (size_t)b * S;
  const int4 mytg = *(const int4*)(tg + 4 * lane);
  const int tgm1 = (lane > 0) ? tg[4 * lane - 1] : -1;
  const float sk1 = (lane > 0 && mytg.x != tgm1) ? 1.f : 0.f;
  const float sk3 = (mytg.y != mytg.x) ? 1.f : 0.f;
  const float sk5 = (mytg.z != mytg.y) ? 1.f : 0.f;
  const float sk7 = (mytg.w != mytg.z) ? 1.f : 0.f;

  float a0 = 0.f, a1 = 0.f, a2 = 0.f, a3 = 0.f, a4 = 0.f, a5 = 0.f, a6 = 0.f,
        a7 = 0.f, a8 = 0.f;
  int E = 0;
  if (R0) {
    if (lane == 0) {
      a0 = qb[0];                                         // t=0 blank
      a1 = __half2float(*(const __half*)gb);              // t=0 first label
    }
  } else {
    const float* ap = alpha_g + (size_t)b * 520 + 8 * lane;
    a0 = ap[0]; a1 = ap[1]; a2 = ap[2]; a3 = ap[3];
    a4 = ap[4]; a5 = ap[5]; a6 = ap[6]; a7 = ap[7];
    a8 = (lane == 63) ? alpha_g[(size_t)b * 520 + 512] : 0.f;
    E = exp_g[b];
  }

  const int t_hi = min(t0 + Tc, len);
  int N = t_hi - (t0 + R0);
  if (N < 0) N = 0;
  const int G = (N + 7) >> 3;

  const char* gpA_ = gb + (size_t)R0 * 544 + 8 * lane;
  const char* gpB_ = gpA_ + 2176;  // 4 rows ahead
  const float* gq_ = qb + R0;

  DECL8(A) DECL8(B)

  __builtin_amdgcn_s_setprio(1);
  asm volatile("s_waitcnt vmcnt(0) lgkmcnt(0)" ::: "memory");
  SB();
  ISS8(A); ISS8(B);  // 20 vmem ops in flight (16-step prefetch)

  for (int g = 0; g < G; g += 2) {
    WAITV(10);
    COMP8(A, N - 8 * g);
    ISS8(A);
    if (g + 1 < G) {
      WAITV(10);
      COMP8(B, N - 8 * (g + 1));
      ISS8(B);
    }
  }
  WAITV(0);
  __builtin_amdgcn_s_setprio(0);

  if constexpr (LAST) {
    fin[8 * lane + 0] = a0; fin[8 * lane + 1] = a1;
    fin[8 * lane + 2] = a2; fin[8 * lane + 3] = a3;
    fin[8 * lane + 4] = a4; fin[8 * lane + 5] = a5;
    fin[8 * lane + 6] = a6; fin[8 * lane + 7] = a7;
    if (lane == 63) fin[512] = a8;
    asm volatile("s_waitcnt lgkmcnt(0)" ::: "memory");
    SB();
    if (lane == 0) {
      const int i1 = 2 * tl;
      const int i2 = (2 * tl - 1 > 0) ? (2 * tl - 1) : 0;
      float v = fin[i1] + ((tl > 0) ? fin[i2] : 0.f);
      v = fmaxf(v, 1e-37f);
      tot[b] = logf(v) + (float)E * 0.6931471805599453f;
    }
  } else {
    float* ap = alpha_g + (size_t)b * 520 + 8 * lane;
    ap[0] = a0; ap[1] = a1; ap[2] = a2; ap[3] = a3;
    ap[4] = a4; ap[5] = a5; ap[6] = a6; ap[7] = a7;
    if (lane == 63) alpha_g[(size_t)b * 520 + 512] = a8;
    if (lane == 0) exp_g[b] = E;
  }
}

// k2 standalone: 8 blocks x 512 thr; wave w = batch blockIdx.x*8+w (2 waves/SIMD)
template <int R0, int LAST>
__global__ __launch_bounds__(512) void k2_std8(
    const char* __restrict__ gbuf, const float* __restrict__ qbuf,
    const int* __restrict__ targets, const int* __restrict__ in_len,
    const int* __restrict__ tgt_len, float* __restrict__ alpha_g,
    int* __restrict__ exp_g, float* __restrict__ tot, int t0, int Tc, int CB,
    int QS, int S) {
  __shared__ float fin[8][520];
  const int w = threadIdx.x >> 6;
  const int b = blockIdx.x * 8 + w;
  k2_body<R0, LAST>(gbuf + (size_t)b * CB * 544, qbuf + (size_t)b * QS,
                    targets, in_len, tgt_len, alpha_g, exp_g, tot, b, t0, Tc,
                    S, fin[w]);
}

// fused: blocks 0..7 = k2 (8 batches each, 2 waves/SIMD); rest = k1 8 rows
template <int R0>
__global__ __launch_bounds__(512) void fused8(
    const float* __restrict__ lp, const int* __restrict__ targets,
    const int* __restrict__ in_len, const int* __restrict__ tgt_len,
    float* __restrict__ alpha_g, int* __restrict__ exp_g,
    float* __restrict__ tot, const char* __restrict__ gprev,
    const float* __restrict__ qprev, char* __restrict__ gcur,
    float* __restrict__ qcur, int t0k2, int t0k1, int T, int Tc, int CB,
    int QS, int S, int TQ8) {
  __shared__ __align__(16) float lds[8192];
  const int w = threadIdx.x >> 6;
  if (blockIdx.x < 8) {
    const int b = blockIdx.x * 8 + w;
    k2_body<R0, 0>(gprev + (size_t)b * CB * 544, qprev + (size_t)b * QS,
                   targets, in_len, tgt_len, alpha_g, exp_g, tot, b, t0k2, Tc,
                   S, nullptr);
    return;
  }
  const int id = blockIdx.x - 8;
  const int b = id / TQ8;
  const int tq = id - b * TQ8;
  k1_body8(lp, targets, gcur, qcur, t0k1, T, CB, QS, S, b, tq,
           lds + w * 1024);
}

// ---------------- k3: -mean over batch ----------------
__global__ void k3_mean(const float* __restrict__ tot, float* __restrict__ out,
                        int B) {
  float v = (threadIdx.x < B) ? tot[threadIdx.x] : 0.0f;
  v = wave_sum64(v);
  if (threadIdx.x == 0) out[0] = -v / (float)B;
}

// ---------------- host ----------------
extern "C" void kernel_launch(void* const* d_in, const int* in_sizes, int n_in,
                              void* d_out, int out_size, void* d_ws,
                              size_t ws_size, hipStream_t stream) {
  const float* lp = (const float*)d_in[0];
  const int* targets = (const int*)d_in[1];
  const int* in_len = (const int*)d_in[2];
  const int* tgt_len = (const int*)d_in[3];
  float* out = (float*)d_out;

  const int B = in_sizes[2];               // 64
  const int S = in_sizes[1] / B;           // 256
  const int C = 1024;
  const int T = (int)((size_t)in_sizes[0] / ((size_t)B * C));  // 2048

  const size_t headf = 64 + 64 + (size_t)64 * 520;  // tot | exp_g | alpha_g
  int Tc = 512;                            // 4 chunks at T=2048
  if (Tc > T) Tc = T;
  int CB = 0, QS = 0;
  while (Tc >= 64) {
    CB = Tc + 64;                          // pad rows cover prefetch over-read
    QS = Tc + 64;
    const size_t need =
        (headf + 2 * (size_t)64 * QS) * 4 + 2 * (size_t)64 * CB * 544;
    if (need <= ws_size || Tc == 64) break;
    Tc >>= 1;
  }
  const int nch = (T + Tc - 1) / Tc;
  const int TQ8 = Tc / 8;

  float* tot = (float*)d_ws;
  int* exp_g = (int*)(tot + 64);
  float* alpha_g = (float*)(exp_g + 64);
  float* q0 = alpha_g + (size_t)64 * 520;
  float* q1 = q0 + (size_t)64 * QS;
  char* g0 = (char*)(q1 + (size_t)64 * QS);
  char* g1 = g0 + (size_t)64 * CB * 544;
  char* gbuf[2] = {g0, g1};
  float* qbuf[2] = {q0, q1};

  if (nch == 1) {
    k1_std8<<<dim3(TQ8, B), 512, 0, stream>>>(lp, targets, gbuf[0], qbuf[0],
                                              0, T, CB, QS, S);
    k2_std8<1, 1><<<8, 512, 0, stream>>>(gbuf[0], qbuf[0], targets, in_len,
                                         tgt_len, alpha_g, exp_g, tot, 0, Tc,
                                         CB, QS, S);
  } else {
    k1_std8<<<dim3(TQ8, B), 512, 0, stream>>>(lp, targets, gbuf[0], qbuf[0],
                                              0, T, CB, QS, S);
    for (int c = 1; c < nch; ++c) {
      const int t0k2 = (c - 1) * Tc;
      const int t0k1 = c * Tc;
      const dim3 grid(8 + TQ8 * B);
      if (c == 1)
        fused8<1><<<grid, 512, 0, stream>>>(
            lp, targets, in_len, tgt_len, alpha_g, exp_g, tot,
            gbuf[(c - 1) & 1], qbuf[(c - 1) & 1], gbuf[c & 1], qbuf[c & 1],
            t0k2, t0k1, T, Tc, CB, QS, S, TQ8);
      else
        fused8<0><<<grid, 512, 0, stream>>>(
            lp, targets, in_len, tgt_len, alpha_g, exp_g, tot,
            gbuf[(c - 1) & 1], qbuf[(c - 1) & 1], gbuf[c & 1], qbuf[c & 1],
            t0k2, t0k1, T, Tc, CB, QS, S, TQ8);
    }
    const int cl = nch - 1;
    k2_std8<0, 1><<<8, 512, 0, stream>>>(gbuf[cl & 1], qbuf[cl & 1], targets,
                                         in_len, tgt_len, alpha_g, exp_g, tot,
                                         cl * Tc, Tc, CB, QS, S);
  }
  k3_mean<<<1, 64, 0, stream>>>(tot, out, B);
}

// Round 20
// 232.835 us; speedup vs baseline: 1.4792x; 1.4792x over previous
//
#include <hip/hip_runtime.h>
#include <math.h>

typedef __attribute__((ext_vector_type(4))) float f32x4;

#define SB() __builtin_amdgcn_sched_barrier(0)
#define WAITV(n)                                              \
  do {                                                        \
    asm volatile("s_waitcnt vmcnt(" #n ")" ::: "memory");     \
    SB();                                                     \
  } while (0)
// inline-asm loads: invisible to SIInsertWaitcnts (no compiler vmcnt(0) drains)
// offset: is 13-bit signed -> immediates kept in {0,1088,2176,3264}
#define LD4(dst, ptr, OFF)                                           \
  asm volatile("global_load_dwordx4 %0, %1, off offset:" OFF         \
               : "=v"(dst) : "v"(ptr) : "memory")
#define LD1(dst, ptr, OFF)                                           \
  asm volatile("global_load_dword %0, %1, off offset:" OFF           \
               : "=v"(dst) : "v"(ptr) : "memory")

__device__ inline float wave_max64(float v) {
#pragma unroll
  for (int off = 32; off > 0; off >>= 1) v = fmaxf(v, __shfl_xor(v, off, 64));
  return v;
}
__device__ inline float wave_sum64(float v) {
#pragma unroll
  for (int off = 32; off > 0; off >>= 1) v += __shfl_xor(v, off, 64);
  return v;
}
// wave64 max via DPP, broadcast via readlane63 (verified r4-r18)
__device__ inline float wave_max_dpp(float x) {
  int xi = __float_as_int(x);
  x = fmaxf(x, __int_as_float(__builtin_amdgcn_update_dpp(xi, xi, 0x111, 0xf, 0xf, false)));
  xi = __float_as_int(x);
  x = fmaxf(x, __int_as_float(__builtin_amdgcn_update_dpp(xi, xi, 0x112, 0xf, 0xf, false)));
  xi = __float_as_int(x);
  x = fmaxf(x, __int_as_float(__builtin_amdgcn_update_dpp(xi, xi, 0x114, 0xf, 0xf, false)));
  xi = __float_as_int(x);
  x = fmaxf(x, __int_as_float(__builtin_amdgcn_update_dpp(xi, xi, 0x118, 0xf, 0xf, false)));
  xi = __float_as_int(x);
  x = fmaxf(x, __int_as_float(__builtin_amdgcn_update_dpp(xi, xi, 0x142, 0xa, 0xf, false)));
  xi = __float_as_int(x);
  x = fmaxf(x, __int_as_float(__builtin_amdgcn_update_dpp(xi, xi, 0x143, 0xc, 0xf, false)));
  return __int_as_float(__builtin_amdgcn_readlane(__float_as_int(x), 63));
}
// lane l <- x from lane l-1; lane 0 <- 0 (DPP wave_shr:1, verified r6-r18)
__device__ inline float lane_shr1(float x) {
  return __int_as_float(__builtin_amdgcn_update_dpp(
      0, __float_as_int(x), 0x138, 0xf, 0xf, true));
}

// ---------------- k1 body: log-softmax + gather -> packed f32 rows ----------
// Row record = 272 floats (1088 B, non-pow2 stride): [0..255] target probs,
// [256] blank, pad. One (b,t) row per wave.
__device__ __forceinline__ void k1_body(
    const float* __restrict__ lp, const int* __restrict__ targets,
    float* __restrict__ gw, int t0, int T, int Tc, int CB, int S,
    int b, int tq, float* rowbuf) {
  const int lane = threadIdx.x & 63;
  const int w = threadIdx.x >> 6;
  const int tloc = tq * 4 + w;
  const int t = t0 + tloc;
  if (t >= T) return;
  const int4 tg4 = *(const int4*)(targets + (size_t)b * S + 4 * lane);

  const float* row = lp + ((size_t)b * T + t) * 1024;
  const float4 v0 = *(const float4*)(row + 4 * lane);
  const float4 v1 = *(const float4*)(row + 256 + 4 * lane);
  const float4 v2 = *(const float4*)(row + 512 + 4 * lane);
  const float4 v3 = *(const float4*)(row + 768 + 4 * lane);
  float mx = fmaxf(fmaxf(fmaxf(v0.x, v0.y), fmaxf(v0.z, v0.w)),
                   fmaxf(fmaxf(v1.x, v1.y), fmaxf(v1.z, v1.w)));
  mx = fmaxf(mx, fmaxf(fmaxf(fmaxf(v2.x, v2.y), fmaxf(v2.z, v2.w)),
                       fmaxf(fmaxf(v3.x, v3.y), fmaxf(v3.z, v3.w))));
  mx = wave_max64(mx);
  float sm = __expf(v0.x - mx) + __expf(v0.y - mx) + __expf(v0.z - mx) +
             __expf(v0.w - mx) + __expf(v1.x - mx) + __expf(v1.y - mx) +
             __expf(v1.z - mx) + __expf(v1.w - mx) + __expf(v2.x - mx) +
             __expf(v2.y - mx) + __expf(v2.z - mx) + __expf(v2.w - mx) +
             __expf(v3.x - mx) + __expf(v3.y - mx) + __expf(v3.z - mx) +
             __expf(v3.w - mx);
  sm = wave_sum64(sm);
  const float lse = mx + __logf(sm);
  *(float4*)(rowbuf + 4 * lane) = v0;
  *(float4*)(rowbuf + 256 + 4 * lane) = v1;
  *(float4*)(rowbuf + 512 + 4 * lane) = v2;
  *(float4*)(rowbuf + 768 + 4 * lane) = v3;
  const float e0 = __expf(rowbuf[tg4.x] - lse);
  const float e1 = __expf(rowbuf[tg4.y] - lse);
  const float e2 = __expf(rowbuf[tg4.z] - lse);
  const float e3 = __expf(rowbuf[tg4.w] - lse);
  float* gr = gw + ((size_t)b * CB + tloc) * 272;
  *(float4*)(gr + 4 * lane) = make_float4(e0, e1, e2, e3);
  if (lane == 0) gr[256] = __expf(rowbuf[0] - lse);
}

__global__ __launch_bounds__(256) void k1_std(
    const float* __restrict__ lp, const int* __restrict__ targets,
    float* __restrict__ gw, int t0, int T, int Tc, int CB, int S) {
  __shared__ __align__(16) float rowbuf4[4][1024];
  k1_body(lp, targets, gw, t0, T, Tc, CB, S, blockIdx.y, blockIdx.x,
          rowbuf4[threadIdx.x >> 6]);
}

// ---------------- k2 body: alpha recursion, 1 wave/batch, 2-set asm pipe ----
#define DECL8(P)                                                     \
  f32x4 P##v0, P##v1, P##v2, P##v3, P##v4, P##v5, P##v6, P##v7;      \
  float P##q0, P##q1, P##q2, P##q3, P##q4, P##q5, P##q6, P##q7;

// two bases 4 rows (4*272 floats = 4352 B) apart; row stride 1088 B
#define ISS8(P)                                                      \
  do {                                                               \
    LD4(P##v0, gpA_, "0");    LD1(P##q0, gqA_, "0");                 \
    LD4(P##v1, gpA_, "1088"); LD1(P##q1, gqA_, "1088");              \
    LD4(P##v2, gpA_, "2176"); LD1(P##q2, gqA_, "2176");              \
    LD4(P##v3, gpA_, "3264"); LD1(P##q3, gqA_, "3264");              \
    LD4(P##v4, gpB_, "0");    LD1(P##q4, gqB_, "0");                 \
    LD4(P##v5, gpB_, "1088"); LD1(P##q5, gqB_, "1088");              \
    LD4(P##v6, gpB_, "2176"); LD1(P##q6, gqB_, "2176");              \
    LD4(P##v7, gpB_, "3264"); LD1(P##q7, gqB_, "3264");              \
    gpA_ += 2176; gqA_ += 2176; gpB_ += 2176; gqB_ += 2176;          \
  } while (0)

#define KSR(pv, qv)                                              \
  {                                                              \
    const float hm1 = lane_shr1(a7);                             \
    const float n0 = (a0 + hm1) * (qv);                          \
    const float n1 = __fmaf_rn(sk1, hm1, a1 + a0) * (pv).x;      \
    const float n2 = (a2 + a1) * (qv);                           \
    const float n3 = __fmaf_rn(sk3, a1, a3 + a2) * (pv).y;       \
    const float n4 = (a4 + a3) * (qv);                           \
    const float n5 = __fmaf_rn(sk5, a3, a5 + a4) * (pv).z;       \
    const float n6 = (a6 + a5) * (qv);                           \
    const float n7 = __fmaf_rn(sk7, a5, a7 + a6) * (pv).w;       \
    const float n8 = (a8 + a7) * (qv);                           \
    a0 = n0; a1 = n1; a2 = n2; a3 = n3; a4 = n4;                 \
    a5 = n5; a6 = n6; a7 = n7; a8 = n8;                          \
  }

#define RESC()                                                            \
  {                                                                       \
    float m_ = fmaxf(fmaxf(fmaxf(fmaxf(a0, a1), fmaxf(a2, a3)),           \
                           fmaxf(fmaxf(a4, a5), fmaxf(a6, a7))), a8);     \
    m_ = wave_max_dpp(m_);                                                \
    const int e_ =                                                        \
        (m_ > 0.f) ? (int)((__float_as_uint(m_) >> 23) & 255u) - 127 : 0; \
    a0 = ldexpf(a0, -e_); a1 = ldexpf(a1, -e_); a2 = ldexpf(a2, -e_);     \
    a3 = ldexpf(a3, -e_); a4 = ldexpf(a4, -e_); a5 = ldexpf(a5, -e_);     \
    a6 = ldexpf(a6, -e_); a7 = ldexpf(a7, -e_); a8 = ldexpf(a8, -e_);     \
    E += e_;                                                              \
  }

#define COMP8(P, rem)                                            \
  do {                                                           \
    if ((rem) >= 8) {                                            \
      KSR(P##v0, P##q0) KSR(P##v1, P##q1) KSR(P##v2, P##q2)      \
      KSR(P##v3, P##q3) KSR(P##v4, P##q4) KSR(P##v5, P##q5)      \
      KSR(P##v6, P##q6) KSR(P##v7, P##q7) RESC()                 \
    } else {                                                     \
      KSR(P##v0, P##q0)                                          \
      if ((rem) > 1) KSR(P##v1, P##q1)                           \
      if ((rem) > 2) KSR(P##v2, P##q2)                           \
      if ((rem) > 3) KSR(P##v3, P##q3)                           \
      if ((rem) > 4) KSR(P##v4, P##q4)                           \
      if ((rem) > 5) KSR(P##v5, P##q5)                           \
      if ((rem) > 6) KSR(P##v6, P##q6)                           \
      RESC()                                                     \
    }                                                            \
  } while (0)

template <int R0, int LAST>
__device__ __forceinline__ void k2_body(
    const float* __restrict__ gb, const int* __restrict__ targets,
    const int* __restrict__ in_len, const int* __restrict__ tgt_len,
    float* __restrict__ alpha_g, int* __restrict__ exp_g,
    float* __restrict__ tot, int b, int t0, int Tc, int S) {
  const int lane = threadIdx.x & 63;
  const int len = in_len[b];
  const int tl = tgt_len[b];
  const int* tg = targets + (size_t)b * S;
  const int4 mytg = *(const int4*)(tg + 4 * lane);
  const int tgm1 = (lane > 0) ? tg[4 * lane - 1] : -1;
  const float sk1 = (lane > 0 && mytg.x != tgm1) ? 1.f : 0.f;
  const float sk3 = (mytg.y != mytg.x) ? 1.f : 0.f;
  const float sk5 = (mytg.z != mytg.y) ? 1.f : 0.f;
  const float sk7 = (mytg.w != mytg.z) ? 1.f : 0.f;

  float a0 = 0.f, a1 = 0.f, a2 = 0.f, a3 = 0.f, a4 = 0.f, a5 = 0.f, a6 = 0.f,
        a7 = 0.f, a8 = 0.f;
  int E = 0;
  if (R0) {
    if (lane == 0) { a0 = gb[256]; a1 = gb[0]; }  // t=0: blank, first label
  } else {
    const float* ap = alpha_g + (size_t)b * 520 + 8 * lane;
    a0 = ap[0]; a1 = ap[1]; a2 = ap[2]; a3 = ap[3];
    a4 = ap[4]; a5 = ap[5]; a6 = ap[6]; a7 = ap[7];
    a8 = (lane == 63) ? alpha_g[(size_t)b * 520 + 512] : 0.f;
    E = exp_g[b];
  }

  const int t_hi = min(t0 + Tc, len);
  int N = t_hi - (t0 + R0);
  if (N < 0) N = 0;
  const int G = (N + 7) >> 3;

  const float* gpA_ = gb + (size_t)R0 * 272 + 4 * lane;
  const float* gqA_ = gb + (size_t)R0 * 272 + 256;
  const float* gpB_ = gpA_ + 1088;  // 4 rows ahead
  const float* gqB_ = gqA_ + 1088;

  DECL8(A) DECL8(B)

  __builtin_amdgcn_s_setprio(1);
  asm volatile("s_waitcnt vmcnt(0) lgkmcnt(0)" ::: "memory");
  SB();
  ISS8(A); ISS8(B);  // 32 vmem ops in flight (16-step prefetch)

  for (int g = 0; g < G; g += 2) {
    WAITV(16);
    COMP8(A, N - 8 * g);
    ISS8(A);
    if (g + 1 < G) {
      WAITV(16);
      COMP8(B, N - 8 * (g + 1));
      ISS8(B);
    }
  }
  WAITV(0);
  __builtin_amdgcn_s_setprio(0);

  if constexpr (LAST) {
    __shared__ float fin[520];
    fin[8 * lane + 0] = a0; fin[8 * lane + 1] = a1;
    fin[8 * lane + 2] = a2; fin[8 * lane + 3] = a3;
    fin[8 * lane + 4] = a4; fin[8 * lane + 5] = a5;
    fin[8 * lane + 6] = a6; fin[8 * lane + 7] = a7;
    if (lane == 63) fin[512] = a8;
    asm volatile("s_waitcnt lgkmcnt(0)" ::: "memory");
    SB();
    if (lane == 0) {
      const int i1 = 2 * tl;
      const int i2 = (2 * tl - 1 > 0) ? (2 * tl - 1) : 0;
      float v = fin[i1] + ((tl > 0) ? fin[i2] : 0.f);
      v = fmaxf(v, 1e-37f);
      tot[b] = logf(v) + (float)E * 0.6931471805599453f;
    }
  } else {
    float* ap = alpha_g + (size_t)b * 520 + 8 * lane;
    ap[0] = a0; ap[1] = a1; ap[2] = a2; ap[3] = a3;
    ap[4] = a4; ap[5] = a5; ap[6] = a6; ap[7] = a7;
    if (lane == 63) alpha_g[(size_t)b * 520 + 512] = a8;
    if (lane == 0) exp_g[b] = E;
  }
}

template <int R0, int LAST>
__global__ __launch_bounds__(64, 1) void k2_std(
    const float* __restrict__ gbuf, const int* __restrict__ targets,
    const int* __restrict__ in_len, const int* __restrict__ tgt_len,
    float* __restrict__ alpha_g, int* __restrict__ exp_g,
    float* __restrict__ tot, int t0, int Tc, int CB, int S) {
  k2_body<R0, LAST>(gbuf + (size_t)blockIdx.x * CB * 272, targets, in_len,
                    tgt_len, alpha_g, exp_g, tot, blockIdx.x, t0, Tc, S);
}

// ---------------- fused: k2 on chunk c-1 (blocks 0..63) || k1 on chunk c ----
template <int R0>
__global__ __launch_bounds__(256, 1) void fused_k(
    const float* __restrict__ lp, const int* __restrict__ targets,
    const int* __restrict__ in_len, const int* __restrict__ tgt_len,
    float* __restrict__ alpha_g, int* __restrict__ exp_g,
    float* __restrict__ tot, const float* __restrict__ gprev,
    float* __restrict__ gcur, int t0k2, int t0k1, int T, int Tc, int CB,
    int S, int TQ4) {
  __shared__ __align__(16) float rowbuf4[4][1024];
  if (blockIdx.x < 64) {
    if (threadIdx.x >= 64) return;
    k2_body<R0, 0>(gprev + (size_t)blockIdx.x * CB * 272, targets, in_len,
                   tgt_len, alpha_g, exp_g, tot, blockIdx.x, t0k2, Tc, S);
    return;
  }
  const int id = blockIdx.x - 64;
  const int b = id / TQ4;
  const int tq = id - b * TQ4;
  k1_body(lp, targets, gcur, t0k1, T, Tc, CB, S, b, tq,
          rowbuf4[threadIdx.x >> 6]);
}

// ---------------- k3: -mean over batch ----------------
__global__ void k3_mean(const float* __restrict__ tot, float* __restrict__ out,
                        int B) {
  float v = (threadIdx.x < B) ? tot[threadIdx.x] : 0.0f;
  v = wave_sum64(v);
  if (threadIdx.x == 0) out[0] = -v / (float)B;
}

// ---------------- host ----------------
extern "C" void kernel_launch(void* const* d_in, const int* in_sizes, int n_in,
                              void* d_out, int out_size, void* d_ws,
                              size_t ws_size, hipStream_t stream) {
  const float* lp = (const float*)d_in[0];
  const int* targets = (const int*)d_in[1];
  const int* in_len = (const int*)d_in[2];
  const int* tgt_len = (const int*)d_in[3];
  float* out = (float*)d_out;

  const int B = in_sizes[2];               // 64
  const int S = in_sizes[1] / B;           // 256
  const int C = 1024;
  const int T = (int)((size_t)in_sizes[0] / ((size_t)B * C));  // 2048

  const size_t headf = 64 + 64 + (size_t)64 * 520;
  int Tc = 512;                            // 4 chunks at T=2048 (r12-proven)
  if (Tc > T) Tc = T;
  while (Tc > 64) {
    const size_t need =
        headf * 4 + 2 * (size_t)64 * (Tc + 64) * 272 * 4;
    if (need <= ws_size) break;
    Tc >>= 1;
  }
  const int CB = Tc + 64;                  // pad rows cover prefetch over-read
  const int nch = (T + Tc - 1) / Tc;
  const int TQ4 = Tc / 4;

  float* tot = (float*)d_ws;
  int* exp_g = (int*)(tot + 64);
  float* alpha_g = (float*)(exp_g + 64);
  float* g0 = alpha_g + (size_t)64 * 520;
  const size_t BUF = (size_t)64 * CB * 272;
  float* gbuf[2] = {g0, g0 + BUF};

  if (nch == 1) {
    k1_std<<<dim3(TQ4, B), 256, 0, stream>>>(lp, targets, gbuf[0], 0, T, Tc,
                                             CB, S);
    k2_std<1, 1><<<B, 64, 0, stream>>>(gbuf[0], targets, in_len, tgt_len,
                                       alpha_g, exp_g, tot, 0, Tc, CB, S);
  } else {
    k1_std<<<dim3(TQ4, B), 256, 0, stream>>>(lp, targets, gbuf[0], 0, T, Tc,
                                             CB, S);
    for (int c = 1; c < nch; ++c) {
      const int t0k2 = (c - 1) * Tc;
      const int t0k1 = c * Tc;
      const dim3 grid(64 + TQ4 * B);
      if (c == 1)
        fused_k<1><<<grid, 256, 0, stream>>>(
            lp, targets, in_len, tgt_len, alpha_g, exp_g, tot,
            gbuf[(c - 1) & 1], gbuf[c & 1], t0k2, t0k1, T, Tc, CB, S, TQ4);
      else
        fused_k<0><<<grid, 256, 0, stream>>>(
            lp, targets, in_len, tgt_len, alpha_g, exp_g, tot,
            gbuf[(c - 1) & 1], gbuf[c & 1], t0k2, t0k1, T, Tc, CB, S, TQ4);
    }
    const int cl = nch - 1;
    k2_std<0, 1><<<B, 64, 0, stream>>>(gbuf[cl & 1], targets, in_len, tgt_len,
                                       alpha_g, exp_g, tot, cl * Tc, Tc, CB,
                                       S);
  }
  k3_mean<<<1, 64, 0, stream>>>(tot, out, B);
}